// Round 13
// baseline (141.830 us; speedup 1.0000x reference)
//
#include <hip/hip_runtime.h>

#define IN_CH 128
#define HID 64
#define ELLW 32        // 32 x ushort = 64B per node row
#define SPILLCAP 4096  // overflow edges (P ~ 0 for this graph)

typedef short v8s __attribute__((ext_vector_type(8)));   // 8 bf16 (4 VGPRs)
typedef float v4f __attribute__((ext_vector_type(4)));   // 4 f32 acc
typedef unsigned long long ull;

// branch-free f32 -> bf16 (round-to-nearest-even), pure uint math
__device__ __forceinline__ unsigned int bf16pair(float a, float b) {
    unsigned int ua = __float_as_uint(a);
    unsigned int ub = __float_as_uint(b);
    ua = (ua + 0x7fffu + ((ua >> 16) & 1u)) >> 16;          // elem0 -> low 16
    ub = (ub + 0x7fffu + ((ub >> 16) & 1u)) & 0xffff0000u;  // elem1 -> high 16
    return ua | ub;
}
__device__ __forceinline__ unsigned short bf16of(float a) {
    unsigned int ua = __float_as_uint(a);
    return (unsigned short)((ua + 0x7fffu + ((ua >> 16) & 1u)) >> 16);
}

// ---------------------------------------------------------------------------
// Kernel 1: fused encoder GEMMs + bucket histogram.
// 512 threads: t<256 = proven R5 VALU encode; t>=256 = per-edge NO-RETURN
// atomicAdd into histmat[col][bucket] (col = bid>>2; bucket = dst>>8).
// No-return atomics run at ~100G/s (vs 13G/s returned) and hide under GEMM.
// ---------------------------------------------------------------------------
__global__ __launch_bounds__(512) void graphmae_encode_hist(
    const float* __restrict__ x, const float* __restrict__ W_rel,
    const float* __restrict__ b_rel, const float* __restrict__ W_root,
    const int* __restrict__ ei,
    unsigned int* __restrict__ y_relw, float* __restrict__ agg,
    int* __restrict__ histmat, int N, int E, int NBUK)
{
    __shared__ float lw[64 * 128];   // k-half of [W_rel | W_root]
    __shared__ float xs[32 * 132];   // 32 x-rows, padded

    const int t  = threadIdx.x;
    const int tc = t & 31;
    const int tr = (t & 255) >> 5;
    const int n0 = blockIdx.x * 32;

    if (t < 256) {
        #pragma unroll
        for (int p = 0; p < 4; ++p) {
            const int row = tr + p * 8;
            const int n   = n0 + row;
            float4 v = make_float4(0.f, 0.f, 0.f, 0.f);
            if (n < N) v = *(const float4*)(x + (size_t)n * IN_CH + tc * 4);
            *(float4*)(xs + row * 132 + tc * 4) = v;
        }
    }

    float acc[4][4];
    #pragma unroll
    for (int i = 0; i < 4; ++i)
        #pragma unroll
        for (int j = 0; j < 4; ++j) acc[i][j] = 0.f;

    for (int kh = 0; kh < 2; ++kh) {
        __syncthreads();
        if (t < 256) {
            #pragma unroll
            for (int p = 0; p < 8; ++p) {
                const int idx  = t + p * 256;
                const int krow = idx >> 5;
                const int col4 = (idx & 31) * 4;
                float4 v;
                if (col4 < HID)
                    v = *(const float4*)(W_rel  + (size_t)(kh * 64 + krow) * HID + col4);
                else
                    v = *(const float4*)(W_root + (size_t)(kh * 64 + krow) * HID + (col4 - HID));
                *(float4*)(lw + idx * 4) = v;
            }
        }
        __syncthreads();

        if (t < 256) {
            #pragma unroll 2
            for (int k = 0; k < 64; k += 4) {
                float4 w0 = *(const float4*)(lw + (k + 0) * 128 + tc * 4);
                float4 w1 = *(const float4*)(lw + (k + 1) * 128 + tc * 4);
                float4 w2 = *(const float4*)(lw + (k + 2) * 128 + tc * 4);
                float4 w3 = *(const float4*)(lw + (k + 3) * 128 + tc * 4);
                const float* w0f = (const float*)&w0;
                const float* w1f = (const float*)&w1;
                const float* w2f = (const float*)&w2;
                const float* w3f = (const float*)&w3;
                #pragma unroll
                for (int i = 0; i < 4; ++i) {
                    const float4 xv = *(const float4*)(xs + (tr * 4 + i) * 132 + kh * 64 + k);
                    const float* xf = (const float*)&xv;
                    #pragma unroll
                    for (int j = 0; j < 4; ++j) {
                        acc[i][j] += xf[0] * w0f[j];
                        acc[i][j] += xf[1] * w1f[j];
                        acc[i][j] += xf[2] * w2f[j];
                        acc[i][j] += xf[3] * w3f[j];
                    }
                }
            }
        } else {
            // ---- histogram: 192 edges per window, no-return atomics ----
            const int tf = t - 256;
            if (tf < 192) {
                const int e = blockIdx.x * 384 + kh * 192 + tf;
                if (e < E) {
                    const int d = ei[E + e];
                    atomicAdd(&histmat[(size_t)(blockIdx.x >> 2) * NBUK + (d >> 8)], 1);
                }
            }
        }
    }

    if (t < 256) {
        const int c0 = (tc & 15) * 4;
        if (tc < 16) {
            #pragma unroll
            for (int i = 0; i < 4; ++i) {
                const int n = n0 + tr * 4 + i;
                if (n < N) {
                    const unsigned int lo = bf16pair(acc[i][0], acc[i][1]);
                    const unsigned int hi = bf16pair(acc[i][2], acc[i][3]);
                    *(uint2*)(y_relw + (size_t)n * 32 + (c0 >> 1)) = make_uint2(lo, hi);
                }
            }
        } else {
            const float4 br = *(const float4*)(b_rel + c0);
            #pragma unroll
            for (int i = 0; i < 4; ++i) {
                const int n = n0 + tr * 4 + i;
                if (n < N)
                    *(float4*)(agg + (size_t)n * HID + c0) =
                        make_float4(acc[i][0] + br.x, acc[i][1] + br.y,
                                    acc[i][2] + br.z, acc[i][3] + br.w);
            }
        }
    }
}

// ---------------------------------------------------------------------------
// Kernel 2: per-bucket scan of histmat columns + cross-bucket lookback.
// Converts histmat[c][b] (counts) in place to absolute write offsets;
// writes bucketbase[b] (segment start) and bucketbase[NBUK] = E.
// ---------------------------------------------------------------------------
__global__ __launch_bounds__(256) void bucket_scan(
    int* __restrict__ histmat, int* __restrict__ bucketbase,
    ull* __restrict__ tpack, int NCOL, int NBUK)
{
    __shared__ int sd[256];
    __shared__ int s_prev;
    const int b = blockIdx.x, t = threadIdx.x;
    const int c0 = t * 2;

    const int v0 = (c0 < NCOL)     ? histmat[(size_t)c0 * NBUK + b] : 0;
    const int v1 = (c0 + 1 < NCOL) ? histmat[(size_t)(c0 + 1) * NBUK + b] : 0;
    const int tsum = v0 + v1;

    sd[t] = tsum;
    __syncthreads();
    for (int off = 1; off < 256; off <<= 1) {
        const int u = (t >= off) ? sd[t - off] : 0;
        __syncthreads();
        sd[t] += u;
        __syncthreads();
    }
    const int total = sd[255];

    if (t == 0) {
        if (b == 0) {
            __hip_atomic_store(&tpack[0], (2ull << 32) | (unsigned)total,
                               __ATOMIC_RELEASE, __HIP_MEMORY_SCOPE_AGENT);
            s_prev = 0;
        } else {
            __hip_atomic_store(&tpack[b], (1ull << 32) | (unsigned)total,
                               __ATOMIC_RELEASE, __HIP_MEMORY_SCOPE_AGENT);
            int prev = 0;
            int i = b - 1;
            while (true) {
                const ull p = __hip_atomic_load(&tpack[i], __ATOMIC_ACQUIRE,
                                                __HIP_MEMORY_SCOPE_AGENT);
                const unsigned st = (unsigned)(p >> 32);
                if (st == 2u) { prev += (int)(unsigned)p; break; }
                if (st == 1u) { prev += (int)(unsigned)p; --i; }
            }
            __hip_atomic_store(&tpack[b], (2ull << 32) | (unsigned)(prev + total),
                               __ATOMIC_RELEASE, __HIP_MEMORY_SCOPE_AGENT);
            s_prev = prev;
        }
        bucketbase[b] = s_prev;
        if (b == (int)gridDim.x - 1) bucketbase[b + 1] = s_prev + total;
    }
    __syncthreads();

    int run = s_prev + sd[t] - tsum;
    if (c0 < NCOL)     histmat[(size_t)c0 * NBUK + b] = run;
    if (c0 + 1 < NCOL) histmat[(size_t)(c0 + 1) * NBUK + b] = run + v0;
}

// ---------------------------------------------------------------------------
// Kernel 3: edge scatter into bucket-sorted order. LDS cursors start at the
// scanned absolute offsets; LDS returned atomics (fast) assign positions.
// Packed edge: (d&255)<<16 | s   (s < 65536).
// ---------------------------------------------------------------------------
__global__ __launch_bounds__(256) void edge_scatter(
    const int* __restrict__ ei, const int* __restrict__ histmat,
    unsigned int* __restrict__ sorted, int E, int NBUK)
{
    __shared__ int cur[256];
    const int t = threadIdx.x, c = blockIdx.x;
    if (t < NBUK) cur[t] = histmat[(size_t)c * NBUK + t];
    __syncthreads();
    const int e0 = c * 1536;
    const int e1 = min(e0 + 1536, E);
    for (int e = e0 + t; e < e1; e += 256) {
        const int d = ei[E + e];
        const int s = ei[e];
        const int idx = atomicAdd(&cur[d >> 8], 1);
        sorted[idx] = ((unsigned)(d & 255) << 16) | (unsigned)s;
    }
}

// ---------------------------------------------------------------------------
// Kernel 4: per-bucket ELL fill, entirely in LDS; coalesced 16KB writeout.
// ---------------------------------------------------------------------------
__global__ __launch_bounds__(256) void bucket_fill(
    const unsigned int* __restrict__ sorted, const int* __restrict__ bucketbase,
    int* __restrict__ deg, unsigned short* __restrict__ slots16,
    int* __restrict__ spillcnt, int2* __restrict__ spill)
{
    __shared__ int cnt[256];
    __shared__ unsigned short sl[256 * ELLW];   // 16KB
    const int t = threadIdx.x, b = blockIdx.x;
    cnt[t] = 0;
    __syncthreads();

    const int s0 = bucketbase[b], s1 = bucketbase[b + 1];
    for (int i = s0 + t; i < s1; i += 256) {
        const unsigned int v = sorted[i];
        const int dl = v >> 16;
        const int r = atomicAdd(&cnt[dl], 1);
        if (r < ELLW) sl[dl * ELLW + r] = (unsigned short)(v & 0xffffu);
        else {
            const int p = atomicAdd(spillcnt, 1);   // statistically never
            if (p < SPILLCAP) spill[p] = make_int2((b << 8) + dl, (int)(v & 0xffffu));
        }
    }
    __syncthreads();

    deg[(b << 8) + t] = cnt[t];
    unsigned int* g = (unsigned int*)slots16 + (size_t)b * 4096;
    const unsigned int* l = (const unsigned int*)sl;
    for (int i = t; i < 4096; i += 256) g[i] = l[i];
}

// ---------------------------------------------------------------------------
// Kernel 5: gather (proven R10-R12 structure). One wave64 per node,
// 8 edge-slots x 8 col-lanes. h = relu(agg + sum) stored bf16.
// ---------------------------------------------------------------------------
__global__ __launch_bounds__(256) void graphmae_gather(
    const int* __restrict__ deg, const unsigned short* __restrict__ slots16,
    const unsigned short* __restrict__ y16, const float* __restrict__ agg,
    const int* __restrict__ spillcnt, const int2* __restrict__ spill,
    unsigned short* __restrict__ h16, int N)
{
    const int n = blockIdx.x * 4 + (threadIdx.x >> 6);
    if (n >= N) return;
    const int lane = threadIdx.x & 63;
    const int es   = lane >> 3;
    const int cl   = lane & 7;

    const int cnt = min(deg[n], ELLW);
    const unsigned short* sp = slots16 + (size_t)n * ELLW;

    float4 a0 = make_float4(0.f, 0.f, 0.f, 0.f);
    float4 a1 = make_float4(0.f, 0.f, 0.f, 0.f);
    if (es == 0) {
        a0 = *(const float4*)(agg + (size_t)n * HID + cl * 8);
        a1 = *(const float4*)(agg + (size_t)n * HID + cl * 8 + 4);
    }

    float acc[8];
    #pragma unroll
    for (int j = 0; j < 8; ++j) acc[j] = 0.f;

    for (int e = es; e < cnt; e += 8) {
        const int s = sp[e];
        const uint4 v = *(const uint4*)(y16 + (size_t)s * HID + cl * 8);
        acc[0] += __uint_as_float(v.x << 16);
        acc[1] += __uint_as_float(v.x & 0xffff0000u);
        acc[2] += __uint_as_float(v.y << 16);
        acc[3] += __uint_as_float(v.y & 0xffff0000u);
        acc[4] += __uint_as_float(v.z << 16);
        acc[5] += __uint_as_float(v.z & 0xffff0000u);
        acc[6] += __uint_as_float(v.w << 16);
        acc[7] += __uint_as_float(v.w & 0xffff0000u);
    }

    const int spN = min(*spillcnt, SPILLCAP);
    for (int i = es; i < spN; i += 8) {
        const int2 e2 = spill[i];
        if (e2.x == n) {
            const uint4 v = *(const uint4*)(y16 + (size_t)e2.y * HID + cl * 8);
            acc[0] += __uint_as_float(v.x << 16);
            acc[1] += __uint_as_float(v.x & 0xffff0000u);
            acc[2] += __uint_as_float(v.y << 16);
            acc[3] += __uint_as_float(v.y & 0xffff0000u);
            acc[4] += __uint_as_float(v.z << 16);
            acc[5] += __uint_as_float(v.z & 0xffff0000u);
            acc[6] += __uint_as_float(v.w << 16);
            acc[7] += __uint_as_float(v.w & 0xffff0000u);
        }
    }

    #pragma unroll
    for (int m = 8; m <= 32; m <<= 1) {
        #pragma unroll
        for (int j = 0; j < 8; ++j) acc[j] += __shfl_xor(acc[j], m);
    }

    if (es == 0) {
        const float h0 = fmaxf(a0.x + acc[0], 0.f);
        const float h1 = fmaxf(a0.y + acc[1], 0.f);
        const float h2 = fmaxf(a0.z + acc[2], 0.f);
        const float h3 = fmaxf(a0.w + acc[3], 0.f);
        const float h4 = fmaxf(a1.x + acc[4], 0.f);
        const float h5 = fmaxf(a1.y + acc[5], 0.f);
        const float h6 = fmaxf(a1.z + acc[6], 0.f);
        const float h7 = fmaxf(a1.w + acc[7], 0.f);
        uint4 o;
        o.x = bf16pair(h0, h1);
        o.y = bf16pair(h2, h3);
        o.z = bf16pair(h4, h5);
        o.w = bf16pair(h6, h7);
        *(uint4*)(h16 + (size_t)n * HID + cl * 8) = o;
    }
}

// ---------------------------------------------------------------------------
// Kernel 6: MFMA decoder (proven). h (bf16) @ W_dec(->bf16) + b_dec -> f32.
// ---------------------------------------------------------------------------
__global__ __launch_bounds__(256) void graphmae_decode(
    const unsigned short* __restrict__ h16, const float* __restrict__ W_dec,
    const float* __restrict__ b_dec, float* __restrict__ out, int N)
{
    __shared__ unsigned short As[64][72];
    __shared__ unsigned short Bs[128][72];

    const int t  = threadIdx.x;
    const int n0 = blockIdx.x * 64;

    {
        const int r = t >> 2, q = t & 3;
        const int n = n0 + r;
        unsigned short* ap = &As[r][q * 16];
        if (n < N) {
            const unsigned short* hp = h16 + (size_t)n * HID + q * 16;
            #pragma unroll
            for (int j = 0; j < 4; ++j)
                *(uint2*)(ap + j * 4) = *(const uint2*)(hp + j * 4);
        } else {
            #pragma unroll
            for (int j = 0; j < 4; ++j) *(uint2*)(ap + j * 4) = make_uint2(0u, 0u);
        }
    }
    #pragma unroll
    for (int p = 0; p < 8; ++p) {
        const int idx = t + p * 256;
        const int k   = idx >> 5;
        const int c4  = (idx & 31) * 4;
        const float4 v = *(const float4*)(W_dec + (size_t)k * IN_CH + c4);
        Bs[c4 + 0][k] = bf16of(v.x);
        Bs[c4 + 1][k] = bf16of(v.y);
        Bs[c4 + 2][k] = bf16of(v.z);
        Bs[c4 + 3][k] = bf16of(v.w);
    }
    __syncthreads();

    const int w    = t >> 6;
    const int lane = t & 63;
    const int mr   = lane & 15;
    const int kg   = lane >> 4;

    v8s afrag[2];
    #pragma unroll
    for (int ks = 0; ks < 2; ++ks)
        afrag[ks] = *(const v8s*)(&As[w * 16 + mr][ks * 32 + kg * 8]);

    const int rbase = n0 + w * 16 + kg * 4;
    #pragma unroll
    for (int ct = 0; ct < 8; ++ct) {
        v4f acc = {0.f, 0.f, 0.f, 0.f};
        #pragma unroll
        for (int ks = 0; ks < 2; ++ks) {
            const v8s b = *(const v8s*)(&Bs[ct * 16 + mr][ks * 32 + kg * 8]);
            acc = __builtin_amdgcn_mfma_f32_16x16x32_bf16(afrag[ks], b, acc, 0, 0, 0);
        }
        const int c  = ct * 16 + mr;
        const float bd = b_dec[c];
        #pragma unroll
        for (int r = 0; r < 4; ++r) {
            const int n = rbase + r;
            if (n < N) out[(size_t)n * IN_CH + c] = acc[r] + bd;
        }
    }
}

// ---------------------------------------------------------------------------
extern "C" void kernel_launch(void* const* d_in, const int* in_sizes, int n_in,
                              void* d_out, int out_size, void* d_ws, size_t ws_size,
                              hipStream_t stream)
{
    const float* x      = (const float*)d_in[0];
    const int*   ei     = (const int*)  d_in[1];   // [2][E] int32
    const float* W_rel  = (const float*)d_in[2];
    const float* b_rel  = (const float*)d_in[3];
    const float* W_root = (const float*)d_in[4];
    const float* W_dec  = (const float*)d_in[5];
    const float* b_dec  = (const float*)d_in[6];
    float* out = (float*)d_out;

    const int N = in_sizes[0] / IN_CH;
    const int E = in_sizes[1] / 2;

    const int nblk_enc = (N + 31) / 32;        // 1563
    const int NBUK     = (N + 255) / 256;      // 196 buckets (dst>>8)
    const int NCOL     = (nblk_enc + 3) / 4;   // 391 scatter columns
    const int NPAD     = NBUK * 256;           // 50176 padded node rows

    unsigned short* y16 = (unsigned short*)d_ws;                   // [N][64] bf16
    float* agg          = (float*)(y16 + (size_t)N * HID);         // [N][64] f32
    unsigned short* h16 = (unsigned short*)(agg + (size_t)N * HID);// [N][64] bf16
    int* deg            = (int*)(h16 + (size_t)N * HID);           // [NPAD]
    unsigned short* slots16 = (unsigned short*)(deg + NPAD);       // [NPAD*ELLW]
    unsigned int* sorted = (unsigned int*)(slots16 + (size_t)NPAD * ELLW); // [E]
    int* histmat   = (int*)(sorted + E);                           // [NCOL*NBUK]
    ull* tpack     = (ull*)(histmat + (size_t)NCOL * NBUK);        // [256]
    int* spillcnt  = (int*)(tpack + 256);                          // [1]+pad
    int2* spill    = (int2*)(spillcnt + 2);                        // [SPILLCAP]
    int* bucketbase = (int*)(spill + SPILLCAP);                    // [NBUK+1]

    // one memset zeroes histmat + tpack + spillcnt (contiguous)
    const size_t zbytes = (size_t)NCOL * NBUK * 4 + 256 * 8 + 8;
    hipMemsetAsync(histmat, 0, zbytes, stream);

    graphmae_encode_hist<<<nblk_enc, 512, 0, stream>>>(
        x, W_rel, b_rel, W_root, ei, (unsigned int*)y16, agg, histmat, N, E, NBUK);

    bucket_scan<<<NBUK, 256, 0, stream>>>(histmat, bucketbase, tpack, NCOL, NBUK);

    edge_scatter<<<NCOL, 256, 0, stream>>>(ei, histmat, sorted, E, NBUK);

    bucket_fill<<<NBUK, 256, 0, stream>>>(sorted, bucketbase, deg, slots16,
                                          spillcnt, spill);

    const int gblk = (N + 3) / 4;
    graphmae_gather<<<gblk, 256, 0, stream>>>(deg, slots16, y16, agg,
                                              spillcnt, spill, h16, N);

    graphmae_decode<<<(N + 63) / 64, 256, 0, stream>>>(h16, W_dec, b_dec, out, N);
}

// Round 14
// 133.906 us; speedup vs baseline: 1.0592x; 1.0592x over previous
//
#include <hip/hip_runtime.h>

#define IN_CH 128
#define HID 64
#define ELLW 32        // 32 x ushort = 64B per node row
#define SPILLCAP 4096  // overflow edges (P ~ 0 for this graph)
#define NSCAT 128      // scatter blocks (columns of histmat)

typedef short v8s __attribute__((ext_vector_type(8)));   // 8 bf16 (4 VGPRs)
typedef float v4f __attribute__((ext_vector_type(4)));   // 4 f32 acc

// branch-free f32 -> bf16 (round-to-nearest-even), pure uint math
__device__ __forceinline__ unsigned int bf16pair(float a, float b) {
    unsigned int ua = __float_as_uint(a);
    unsigned int ub = __float_as_uint(b);
    ua = (ua + 0x7fffu + ((ua >> 16) & 1u)) >> 16;
    ub = (ub + 0x7fffu + ((ub >> 16) & 1u)) & 0xffff0000u;
    return ua | ub;
}
__device__ __forceinline__ unsigned short bf16of(float a) {
    unsigned int ua = __float_as_uint(a);
    return (unsigned short)((ua + 0x7fffu + ((ua >> 16) & 1u)) >> 16);
}

// ---------------------------------------------------------------------------
// Kernel 1: MFMA encoder (R6's correctness-proven kernel, now standalone so
// its duration is finally isolated in rocprof).
//   y16[n][c] = bf16( x[n][:] @ W_rel[:][c] )          c in 0..63
//   agg[n][c] = x[n][:] @ W_root[:][c] + b_rel[c]      f32 gather-init
// ---------------------------------------------------------------------------
__global__ __launch_bounds__(256) void graphmae_encode(
    const float* __restrict__ x, const float* __restrict__ W_rel,
    const float* __restrict__ b_rel, const float* __restrict__ W_root,
    unsigned short* __restrict__ y16, float* __restrict__ agg, int N)
{
    __shared__ unsigned short As[64][136];    // x tile, bf16
    __shared__ unsigned short Bs[128][136];   // [W_rel|W_root]^T, bf16: [col][k]

    const int t  = threadIdx.x;
    const int n0 = blockIdx.x * 64;

    {
        const int r = t >> 2, q = t & 3;
        const int n = n0 + r;
        unsigned short* ap = &As[r][q * 32];
        if (n < N) {
            const float* xp = x + (size_t)n * IN_CH + q * 32;
            #pragma unroll
            for (int j = 0; j < 8; ++j) {
                const float4 v = *(const float4*)(xp + j * 4);
                *(uint2*)(ap + j * 4) =
                    make_uint2(bf16pair(v.x, v.y), bf16pair(v.z, v.w));
            }
        } else {
            #pragma unroll
            for (int j = 0; j < 8; ++j) *(uint2*)(ap + j * 4) = make_uint2(0u, 0u);
        }
    }
    #pragma unroll
    for (int p = 0; p < 16; ++p) {
        const int idx = t + p * 256;        // float4 id 0..4095
        const int k   = idx >> 5;           // 0..127
        const int c4  = (idx & 31) * 4;     // 0..124
        float4 v;
        if (c4 < HID) v = *(const float4*)(W_rel  + (size_t)k * HID + c4);
        else          v = *(const float4*)(W_root + (size_t)k * HID + (c4 - HID));
        Bs[c4 + 0][k] = bf16of(v.x);
        Bs[c4 + 1][k] = bf16of(v.y);
        Bs[c4 + 2][k] = bf16of(v.z);
        Bs[c4 + 3][k] = bf16of(v.w);
    }
    __syncthreads();

    const int w    = t >> 6;
    const int lane = t & 63;
    const int mr   = lane & 15;
    const int kg   = lane >> 4;

    v8s afrag[4];
    #pragma unroll
    for (int ks = 0; ks < 4; ++ks)
        afrag[ks] = *(const v8s*)(&As[w * 16 + mr][ks * 32 + kg * 8]);

    const int rbase = n0 + w * 16 + kg * 4;
    #pragma unroll
    for (int ct = 0; ct < 8; ++ct) {
        v4f acc = {0.f, 0.f, 0.f, 0.f};
        #pragma unroll
        for (int ks = 0; ks < 4; ++ks) {
            const v8s b = *(const v8s*)(&Bs[ct * 16 + mr][ks * 32 + kg * 8]);
            acc = __builtin_amdgcn_mfma_f32_16x16x32_bf16(afrag[ks], b, acc, 0, 0, 0);
        }
        const int c = ct * 16 + mr;
        if (ct < 4) {
            #pragma unroll
            for (int r = 0; r < 4; ++r) {
                const int n = rbase + r;
                if (n < N) y16[(size_t)n * HID + c] = bf16of(acc[r]);
            }
        } else {
            const float br = b_rel[c - HID];
            #pragma unroll
            for (int r = 0; r < 4; ++r) {
                const int n = rbase + r;
                if (n < N) agg[(size_t)n * HID + (c - HID)] = acc[r] + br;
            }
        }
    }
}

// ---------------------------------------------------------------------------
// Kernel 2: per-block LDS histogram -> histmat[bucket][block] (bucket-major).
// No global returned atomics; exclusive stores (each cell written once).
// ---------------------------------------------------------------------------
__global__ __launch_bounds__(256) void edge_hist(
    const int* __restrict__ ei, int* __restrict__ histmat,
    int E, int NBUK, int CE)
{
    __shared__ int lhist[256];
    const int t = threadIdx.x, c = blockIdx.x;
    lhist[t] = 0;
    __syncthreads();
    const int e1 = min(E, (c + 1) * CE);
    for (int e = c * CE + t; e < e1; e += 256)
        atomicAdd(&lhist[ei[E + e] >> 8], 1);      // LDS atomic — fast
    __syncthreads();
    if (t < NBUK) histmat[(size_t)t * NSCAT + c] = lhist[t];
}

// ---------------------------------------------------------------------------
// Kernel 3: single-block flat exclusive scan over histmat (bucket-major,
// NBUK*NSCAT ints). No lookback, no cross-block anything.
// ---------------------------------------------------------------------------
__global__ __launch_bounds__(256) void hist_scan(int* __restrict__ F, int NT)
{
    __shared__ int sd[256];
    __shared__ int s_base;
    const int t = threadIdx.x;
    if (t == 0) s_base = 0;
    __syncthreads();

    for (int base = 0; base < NT; base += 1024) {
        int d[4];
        const int i0 = base + t * 4;
        #pragma unroll
        for (int j = 0; j < 4; ++j) d[j] = (i0 + j < NT) ? F[i0 + j] : 0;
        const int tsum = d[0] + d[1] + d[2] + d[3];
        sd[t] = tsum;
        __syncthreads();
        for (int off = 1; off < 256; off <<= 1) {
            const int u = (t >= off) ? sd[t - off] : 0;
            __syncthreads();
            sd[t] += u;
            __syncthreads();
        }
        int run = s_base + sd[t] - tsum;
        #pragma unroll
        for (int j = 0; j < 4; ++j) {
            if (i0 + j < NT) F[i0 + j] = run;
            run += d[j];
        }
        __syncthreads();
        if (t == 255) s_base += sd[255];
        __syncthreads();
    }
}

// ---------------------------------------------------------------------------
// Kernel 4: scatter edges into bucket-sorted order. LDS cursors seeded from
// scanned histmat; LDS returned atomics assign positions (fast).
// Packed edge: (d&255)<<16 | s   (s < 65536).
// ---------------------------------------------------------------------------
__global__ __launch_bounds__(256) void edge_scatter(
    const int* __restrict__ ei, const int* __restrict__ histmat,
    unsigned int* __restrict__ sorted, int E, int NBUK, int CE)
{
    __shared__ int cur[256];
    const int t = threadIdx.x, c = blockIdx.x;
    if (t < NBUK) cur[t] = histmat[(size_t)t * NSCAT + c];
    __syncthreads();
    const int e1 = min(E, (c + 1) * CE);
    for (int e = c * CE + t; e < e1; e += 256) {
        const int d = ei[E + e];
        const int s = ei[e];
        const int idx = atomicAdd(&cur[d >> 8], 1);
        sorted[idx] = ((unsigned)(d & 255) << 16) | (unsigned)s;
    }
}

// ---------------------------------------------------------------------------
// Kernel 5: per-bucket ELL fill, entirely in LDS; coalesced 16KB writeout.
// Segment bounds come straight from the scanned histmat column 0.
// ---------------------------------------------------------------------------
__global__ __launch_bounds__(256) void bucket_fill(
    const unsigned int* __restrict__ sorted, const int* __restrict__ histmat,
    int* __restrict__ deg, unsigned short* __restrict__ slots16,
    int* __restrict__ spillcnt, int2* __restrict__ spill, int E, int NBUK)
{
    __shared__ int cnt[256];
    __shared__ unsigned short sl[256 * ELLW];   // 16KB
    const int t = threadIdx.x, b = blockIdx.x;
    cnt[t] = 0;
    __syncthreads();

    const int s0 = histmat[(size_t)b * NSCAT];
    const int s1 = (b + 1 < NBUK) ? histmat[(size_t)(b + 1) * NSCAT] : E;
    for (int i = s0 + t; i < s1; i += 256) {
        const unsigned int v = sorted[i];
        const int dl = v >> 16;
        const int r = atomicAdd(&cnt[dl], 1);
        if (r < ELLW) sl[dl * ELLW + r] = (unsigned short)(v & 0xffffu);
        else {
            const int p = atomicAdd(spillcnt, 1);   // statistically never
            if (p < SPILLCAP) spill[p] = make_int2((b << 8) + dl, (int)(v & 0xffffu));
        }
    }
    __syncthreads();

    deg[(b << 8) + t] = cnt[t];
    unsigned int* g = (unsigned int*)slots16 + (size_t)b * 4096;
    const unsigned int* l = (const unsigned int*)sl;
    for (int i = t; i < 4096; i += 256) g[i] = l[i];
}

// ---------------------------------------------------------------------------
// Kernel 6: gather (proven R10-R12 structure). One wave64 per node,
// 8 edge-slots x 8 col-lanes. h = relu(agg + sum) stored bf16.
// ---------------------------------------------------------------------------
__global__ __launch_bounds__(256) void graphmae_gather(
    const int* __restrict__ deg, const unsigned short* __restrict__ slots16,
    const unsigned short* __restrict__ y16, const float* __restrict__ agg,
    const int* __restrict__ spillcnt, const int2* __restrict__ spill,
    unsigned short* __restrict__ h16, int N)
{
    const int n = blockIdx.x * 4 + (threadIdx.x >> 6);
    if (n >= N) return;
    const int lane = threadIdx.x & 63;
    const int es   = lane >> 3;
    const int cl   = lane & 7;

    const int cnt = min(deg[n], ELLW);
    const unsigned short* sp = slots16 + (size_t)n * ELLW;

    float4 a0 = make_float4(0.f, 0.f, 0.f, 0.f);
    float4 a1 = make_float4(0.f, 0.f, 0.f, 0.f);
    if (es == 0) {
        a0 = *(const float4*)(agg + (size_t)n * HID + cl * 8);
        a1 = *(const float4*)(agg + (size_t)n * HID + cl * 8 + 4);
    }

    float acc[8];
    #pragma unroll
    for (int j = 0; j < 8; ++j) acc[j] = 0.f;

    for (int e = es; e < cnt; e += 8) {
        const int s = sp[e];
        const uint4 v = *(const uint4*)(y16 + (size_t)s * HID + cl * 8);
        acc[0] += __uint_as_float(v.x << 16);
        acc[1] += __uint_as_float(v.x & 0xffff0000u);
        acc[2] += __uint_as_float(v.y << 16);
        acc[3] += __uint_as_float(v.y & 0xffff0000u);
        acc[4] += __uint_as_float(v.z << 16);
        acc[5] += __uint_as_float(v.z & 0xffff0000u);
        acc[6] += __uint_as_float(v.w << 16);
        acc[7] += __uint_as_float(v.w & 0xffff0000u);
    }

    const int spN = min(*spillcnt, SPILLCAP);
    for (int i = es; i < spN; i += 8) {
        const int2 e2 = spill[i];
        if (e2.x == n) {
            const uint4 v = *(const uint4*)(y16 + (size_t)e2.y * HID + cl * 8);
            acc[0] += __uint_as_float(v.x << 16);
            acc[1] += __uint_as_float(v.x & 0xffff0000u);
            acc[2] += __uint_as_float(v.y << 16);
            acc[3] += __uint_as_float(v.y & 0xffff0000u);
            acc[4] += __uint_as_float(v.z << 16);
            acc[5] += __uint_as_float(v.z & 0xffff0000u);
            acc[6] += __uint_as_float(v.w << 16);
            acc[7] += __uint_as_float(v.w & 0xffff0000u);
        }
    }

    #pragma unroll
    for (int m = 8; m <= 32; m <<= 1) {
        #pragma unroll
        for (int j = 0; j < 8; ++j) acc[j] += __shfl_xor(acc[j], m);
    }

    if (es == 0) {
        const float h0 = fmaxf(a0.x + acc[0], 0.f);
        const float h1 = fmaxf(a0.y + acc[1], 0.f);
        const float h2 = fmaxf(a0.z + acc[2], 0.f);
        const float h3 = fmaxf(a0.w + acc[3], 0.f);
        const float h4 = fmaxf(a1.x + acc[4], 0.f);
        const float h5 = fmaxf(a1.y + acc[5], 0.f);
        const float h6 = fmaxf(a1.z + acc[6], 0.f);
        const float h7 = fmaxf(a1.w + acc[7], 0.f);
        uint4 o;
        o.x = bf16pair(h0, h1);
        o.y = bf16pair(h2, h3);
        o.z = bf16pair(h4, h5);
        o.w = bf16pair(h6, h7);
        *(uint4*)(h16 + (size_t)n * HID + cl * 8) = o;
    }
}

// ---------------------------------------------------------------------------
// Kernel 7: MFMA decoder (proven). h (bf16) @ W_dec(->bf16) + b_dec -> f32.
// ---------------------------------------------------------------------------
__global__ __launch_bounds__(256) void graphmae_decode(
    const unsigned short* __restrict__ h16, const float* __restrict__ W_dec,
    const float* __restrict__ b_dec, float* __restrict__ out, int N)
{
    __shared__ unsigned short As[64][72];
    __shared__ unsigned short Bs[128][72];

    const int t  = threadIdx.x;
    const int n0 = blockIdx.x * 64;

    {
        const int r = t >> 2, q = t & 3;
        const int n = n0 + r;
        unsigned short* ap = &As[r][q * 16];
        if (n < N) {
            const unsigned short* hp = h16 + (size_t)n * HID + q * 16;
            #pragma unroll
            for (int j = 0; j < 4; ++j)
                *(uint2*)(ap + j * 4) = *(const uint2*)(hp + j * 4);
        } else {
            #pragma unroll
            for (int j = 0; j < 4; ++j) *(uint2*)(ap + j * 4) = make_uint2(0u, 0u);
        }
    }
    #pragma unroll
    for (int p = 0; p < 8; ++p) {
        const int idx = t + p * 256;
        const int k   = idx >> 5;
        const int c4  = (idx & 31) * 4;
        const float4 v = *(const float4*)(W_dec + (size_t)k * IN_CH + c4);
        Bs[c4 + 0][k] = bf16of(v.x);
        Bs[c4 + 1][k] = bf16of(v.y);
        Bs[c4 + 2][k] = bf16of(v.z);
        Bs[c4 + 3][k] = bf16of(v.w);
    }
    __syncthreads();

    const int w    = t >> 6;
    const int lane = t & 63;
    const int mr   = lane & 15;
    const int kg   = lane >> 4;

    v8s afrag[2];
    #pragma unroll
    for (int ks = 0; ks < 2; ++ks)
        afrag[ks] = *(const v8s*)(&As[w * 16 + mr][ks * 32 + kg * 8]);

    const int rbase = n0 + w * 16 + kg * 4;
    #pragma unroll
    for (int ct = 0; ct < 8; ++ct) {
        v4f acc = {0.f, 0.f, 0.f, 0.f};
        #pragma unroll
        for (int ks = 0; ks < 2; ++ks) {
            const v8s b = *(const v8s*)(&Bs[ct * 16 + mr][ks * 32 + kg * 8]);
            acc = __builtin_amdgcn_mfma_f32_16x16x32_bf16(afrag[ks], b, acc, 0, 0, 0);
        }
        const int c  = ct * 16 + mr;
        const float bd = b_dec[c];
        #pragma unroll
        for (int r = 0; r < 4; ++r) {
            const int n = rbase + r;
            if (n < N) out[(size_t)n * IN_CH + c] = acc[r] + bd;
        }
    }
}

// ---------------------------------------------------------------------------
extern "C" void kernel_launch(void* const* d_in, const int* in_sizes, int n_in,
                              void* d_out, int out_size, void* d_ws, size_t ws_size,
                              hipStream_t stream)
{
    const float* x      = (const float*)d_in[0];
    const int*   ei     = (const int*)  d_in[1];   // [2][E] int32
    const float* W_rel  = (const float*)d_in[2];
    const float* b_rel  = (const float*)d_in[3];
    const float* W_root = (const float*)d_in[4];
    const float* W_dec  = (const float*)d_in[5];
    const float* b_dec  = (const float*)d_in[6];
    float* out = (float*)d_out;

    const int N = in_sizes[0] / IN_CH;
    const int E = in_sizes[1] / 2;

    const int NBUK = (N + 255) / 256;      // 196 buckets (dst>>8)
    const int NPAD = NBUK * 256;           // 50176 padded node rows
    const int CE   = (E + NSCAT - 1) / NSCAT;

    unsigned short* y16 = (unsigned short*)d_ws;                   // [N][64] bf16
    float* agg          = (float*)(y16 + (size_t)N * HID);         // [N][64] f32
    unsigned short* h16 = (unsigned short*)(agg + (size_t)N * HID);// [N][64] bf16
    int* deg            = (int*)(h16 + (size_t)N * HID);           // [NPAD]
    unsigned short* slots16 = (unsigned short*)(deg + NPAD);       // [NPAD*ELLW]
    unsigned int* sorted = (unsigned int*)(slots16 + (size_t)NPAD * ELLW); // [E]
    int* histmat   = (int*)(sorted + E);                           // [NBUK*NSCAT]
    int* spillcnt  = histmat + (size_t)NBUK * NSCAT;               // [2]
    int2* spill    = (int2*)(spillcnt + 2);                        // [SPILLCAP]

    hipMemsetAsync(spillcnt, 0, sizeof(int), stream);

    const int nblk64 = (N + 63) / 64;
    graphmae_encode<<<nblk64, 256, 0, stream>>>(x, W_rel, b_rel, W_root,
                                                y16, agg, N);
    edge_hist   <<<NSCAT, 256, 0, stream>>>(ei, histmat, E, NBUK, CE);
    hist_scan   <<<1,     256, 0, stream>>>(histmat, NBUK * NSCAT);
    edge_scatter<<<NSCAT, 256, 0, stream>>>(ei, histmat, sorted, E, NBUK, CE);
    bucket_fill <<<NBUK,  256, 0, stream>>>(sorted, histmat, deg, slots16,
                                            spillcnt, spill, E, NBUK);

    const int gblk = (N + 3) / 4;
    graphmae_gather<<<gblk, 256, 0, stream>>>(deg, slots16, y16, agg,
                                              spillcnt, spill, h16, N);
    graphmae_decode<<<nblk64, 256, 0, stream>>>(h16, W_dec, b_dec, out, N);
}

// Round 15
// 112.899 us; speedup vs baseline: 1.2563x; 1.1861x over previous
//
#include <hip/hip_runtime.h>

#define IN_CH 128
#define HID 64
#define ELLW 32        // 32 x ushort = 64B per node row
#define SPILLCAP 4096  // overflow edges (P ~ 0 for this graph)
#define NSCAT 64       // scatter blocks (low bucket-cursor contention)
#define BCAP 3584      // fixed region capacity per 256-node bucket (mean 3061, +9 sigma)

typedef short v8s __attribute__((ext_vector_type(8)));   // 8 bf16 (4 VGPRs)
typedef float v4f __attribute__((ext_vector_type(4)));   // 4 f32 acc

// branch-free f32 -> bf16 (round-to-nearest-even), pure uint math
__device__ __forceinline__ unsigned int bf16pair(float a, float b) {
    unsigned int ua = __float_as_uint(a);
    unsigned int ub = __float_as_uint(b);
    ua = (ua + 0x7fffu + ((ua >> 16) & 1u)) >> 16;          // elem0 -> low 16
    ub = (ub + 0x7fffu + ((ub >> 16) & 1u)) & 0xffff0000u;  // elem1 -> high 16
    return ua | ub;
}
__device__ __forceinline__ unsigned short bf16of(float a) {
    unsigned int ua = __float_as_uint(a);
    return (unsigned short)((ua + 0x7fffu + ((ua >> 16) & 1u)) >> 16);
}

// ---------------------------------------------------------------------------
// Kernel 1: fused encoder GEMMs (VALU f32, R5 proven form, standalone).
//   y16[n][c] = bf16( x[n][:] @ W_rel[:][c] )       packed bf16
//   agg[n][c] = x[n][:] @ W_root[:][c] + b_rel[c]   f32 gather-init
// ---------------------------------------------------------------------------
__global__ __launch_bounds__(256) void graphmae_encode(
    const float* __restrict__ x, const float* __restrict__ W_rel,
    const float* __restrict__ b_rel, const float* __restrict__ W_root,
    unsigned int* __restrict__ y_relw, float* __restrict__ agg, int N)
{
    __shared__ float lw[64 * 128];   // k-half of [W_rel | W_root]
    __shared__ float xs[32 * 132];   // 32 x-rows, padded

    const int t  = threadIdx.x;
    const int tc = t & 31;
    const int tr = t >> 5;
    const int n0 = blockIdx.x * 32;

    #pragma unroll
    for (int p = 0; p < 4; ++p) {
        const int row = tr + p * 8;
        const int n   = n0 + row;
        float4 v = make_float4(0.f, 0.f, 0.f, 0.f);
        if (n < N) v = *(const float4*)(x + (size_t)n * IN_CH + tc * 4);
        *(float4*)(xs + row * 132 + tc * 4) = v;
    }

    float acc[4][4];
    #pragma unroll
    for (int i = 0; i < 4; ++i)
        #pragma unroll
        for (int j = 0; j < 4; ++j) acc[i][j] = 0.f;

    for (int kh = 0; kh < 2; ++kh) {
        __syncthreads();
        #pragma unroll
        for (int p = 0; p < 8; ++p) {
            const int idx  = t + p * 256;
            const int krow = idx >> 5;
            const int col4 = (idx & 31) * 4;
            float4 v;
            if (col4 < HID)
                v = *(const float4*)(W_rel  + (size_t)(kh * 64 + krow) * HID + col4);
            else
                v = *(const float4*)(W_root + (size_t)(kh * 64 + krow) * HID + (col4 - HID));
            *(float4*)(lw + idx * 4) = v;
        }
        __syncthreads();

        #pragma unroll 2
        for (int k = 0; k < 64; k += 4) {
            float4 w0 = *(const float4*)(lw + (k + 0) * 128 + tc * 4);
            float4 w1 = *(const float4*)(lw + (k + 1) * 128 + tc * 4);
            float4 w2 = *(const float4*)(lw + (k + 2) * 128 + tc * 4);
            float4 w3 = *(const float4*)(lw + (k + 3) * 128 + tc * 4);
            const float* w0f = (const float*)&w0;
            const float* w1f = (const float*)&w1;
            const float* w2f = (const float*)&w2;
            const float* w3f = (const float*)&w3;
            #pragma unroll
            for (int i = 0; i < 4; ++i) {
                const float4 xv = *(const float4*)(xs + (tr * 4 + i) * 132 + kh * 64 + k);
                const float* xf = (const float*)&xv;
                #pragma unroll
                for (int j = 0; j < 4; ++j) {
                    acc[i][j] += xf[0] * w0f[j];
                    acc[i][j] += xf[1] * w1f[j];
                    acc[i][j] += xf[2] * w2f[j];
                    acc[i][j] += xf[3] * w3f[j];
                }
            }
        }
    }

    const int c0 = (tc & 15) * 4;
    if (tc < 16) {
        #pragma unroll
        for (int i = 0; i < 4; ++i) {
            const int n = n0 + tr * 4 + i;
            if (n < N) {
                const unsigned int lo = bf16pair(acc[i][0], acc[i][1]);
                const unsigned int hi = bf16pair(acc[i][2], acc[i][3]);
                *(uint2*)(y_relw + (size_t)n * 32 + (c0 >> 1)) = make_uint2(lo, hi);
            }
        }
    } else {
        const float4 br = *(const float4*)(b_rel + c0);
        #pragma unroll
        for (int i = 0; i < 4; ++i) {
            const int n = n0 + tr * 4 + i;
            if (n < N)
                *(float4*)(agg + (size_t)n * HID + c0) =
                    make_float4(acc[i][0] + br.x, acc[i][1] + br.y,
                                acc[i][2] + br.z, acc[i][3] + br.w);
        }
    }
}

// ---------------------------------------------------------------------------
// Kernel 2: bucket scatter, scan-free. Per block: LDS histogram of its edge
// chunk -> ONE returned global atomic per (block,bucket) reserves space in
// bucket b's fixed region [b*BCAP ...) -> pass 2 writes packed edges at LDS
// cursor positions. 64x196 = 12.5K returned atomics total (vs 600K).
// Region overflow (P ~ 0) -> spill list.
// ---------------------------------------------------------------------------
__global__ __launch_bounds__(256) void edge_scatter(
    const int* __restrict__ ei, int* __restrict__ bucketcur,
    unsigned int* __restrict__ sorted, int* __restrict__ spillcnt,
    int2* __restrict__ spill, int E, int NBUK, int CE)
{
    __shared__ int lh[256];    // per-bucket local count
    __shared__ int lcur[256];  // reserved base, then running cursor
    const int t = threadIdx.x, c = blockIdx.x;
    lh[t] = 0;
    __syncthreads();

    const int e0 = c * CE, e1 = min(E, e0 + CE);
    for (int e = e0 + t; e < e1; e += 256)
        atomicAdd(&lh[ei[E + e] >> 8], 1);          // LDS atomic — fast
    __syncthreads();

    if (t < NBUK) {
        const int cnt = lh[t];
        lcur[t] = (cnt > 0) ? atomicAdd(&bucketcur[t], cnt) : 0;
    }
    __syncthreads();

    for (int e = e0 + t; e < e1; e += 256) {
        const int d = ei[E + e];
        const int s = ei[e];
        const int b = d >> 8;
        const int pos = atomicAdd(&lcur[b], 1);     // LDS atomic — fast
        if (pos < BCAP) {
            sorted[(size_t)b * BCAP + pos] =
                ((unsigned)(d & 255) << 16) | (unsigned)s;
        } else {
            const int p = atomicAdd(spillcnt, 1);   // statistically never
            if (p < SPILLCAP) spill[p] = make_int2(d, s);
        }
    }
}

// ---------------------------------------------------------------------------
// Kernel 3: per-bucket ELL fill, entirely in LDS; coalesced 16KB writeout.
// ---------------------------------------------------------------------------
__global__ __launch_bounds__(256) void bucket_fill(
    const unsigned int* __restrict__ sorted, const int* __restrict__ bucketcur,
    int* __restrict__ deg, unsigned short* __restrict__ slots16,
    int* __restrict__ spillcnt, int2* __restrict__ spill)
{
    __shared__ int cnt[256];
    __shared__ unsigned short sl[256 * ELLW];   // 16KB
    const int t = threadIdx.x, b = blockIdx.x;
    cnt[t] = 0;
    __syncthreads();

    const int m = min(bucketcur[b], BCAP);
    const unsigned int* src = sorted + (size_t)b * BCAP;
    for (int i = t; i < m; i += 256) {
        const unsigned int v = src[i];
        const int dl = v >> 16;
        const int r = atomicAdd(&cnt[dl], 1);       // LDS atomic — fast
        if (r < ELLW) sl[dl * ELLW + r] = (unsigned short)(v & 0xffffu);
        else {
            const int p = atomicAdd(spillcnt, 1);   // statistically never
            if (p < SPILLCAP) spill[p] = make_int2((b << 8) + dl, (int)(v & 0xffffu));
        }
    }
    __syncthreads();

    deg[(b << 8) + t] = cnt[t];
    unsigned int* g = (unsigned int*)slots16 + (size_t)b * 4096;
    const unsigned int* l = (const unsigned int*)sl;
    for (int i = t; i < 4096; i += 256) g[i] = l[i];
}

// ---------------------------------------------------------------------------
// Kernel 4: gather (proven R10-R14 structure). One wave64 per node,
// 8 edge-slots x 8 col-lanes. h = relu(agg + sum) stored bf16.
// ---------------------------------------------------------------------------
__global__ __launch_bounds__(256) void graphmae_gather(
    const int* __restrict__ deg, const unsigned short* __restrict__ slots16,
    const unsigned short* __restrict__ y16, const float* __restrict__ agg,
    const int* __restrict__ spillcnt, const int2* __restrict__ spill,
    unsigned short* __restrict__ h16, int N)
{
    const int n = blockIdx.x * 4 + (threadIdx.x >> 6);
    if (n >= N) return;
    const int lane = threadIdx.x & 63;
    const int es   = lane >> 3;
    const int cl   = lane & 7;

    const int cnt = min(deg[n], ELLW);
    const unsigned short* sp = slots16 + (size_t)n * ELLW;

    float4 a0 = make_float4(0.f, 0.f, 0.f, 0.f);
    float4 a1 = make_float4(0.f, 0.f, 0.f, 0.f);
    if (es == 0) {
        a0 = *(const float4*)(agg + (size_t)n * HID + cl * 8);
        a1 = *(const float4*)(agg + (size_t)n * HID + cl * 8 + 4);
    }

    float acc[8];
    #pragma unroll
    for (int j = 0; j < 8; ++j) acc[j] = 0.f;

    for (int e = es; e < cnt; e += 8) {
        const int s = sp[e];
        const uint4 v = *(const uint4*)(y16 + (size_t)s * HID + cl * 8);
        acc[0] += __uint_as_float(v.x << 16);
        acc[1] += __uint_as_float(v.x & 0xffff0000u);
        acc[2] += __uint_as_float(v.y << 16);
        acc[3] += __uint_as_float(v.y & 0xffff0000u);
        acc[4] += __uint_as_float(v.z << 16);
        acc[5] += __uint_as_float(v.z & 0xffff0000u);
        acc[6] += __uint_as_float(v.w << 16);
        acc[7] += __uint_as_float(v.w & 0xffff0000u);
    }

    const int spN = min(*spillcnt, SPILLCAP);
    for (int i = es; i < spN; i += 8) {
        const int2 e2 = spill[i];
        if (e2.x == n) {
            const uint4 v = *(const uint4*)(y16 + (size_t)e2.y * HID + cl * 8);
            acc[0] += __uint_as_float(v.x << 16);
            acc[1] += __uint_as_float(v.x & 0xffff0000u);
            acc[2] += __uint_as_float(v.y << 16);
            acc[3] += __uint_as_float(v.y & 0xffff0000u);
            acc[4] += __uint_as_float(v.z << 16);
            acc[5] += __uint_as_float(v.z & 0xffff0000u);
            acc[6] += __uint_as_float(v.w << 16);
            acc[7] += __uint_as_float(v.w & 0xffff0000u);
        }
    }

    #pragma unroll
    for (int m = 8; m <= 32; m <<= 1) {
        #pragma unroll
        for (int j = 0; j < 8; ++j) acc[j] += __shfl_xor(acc[j], m);
    }

    if (es == 0) {
        const float h0 = fmaxf(a0.x + acc[0], 0.f);
        const float h1 = fmaxf(a0.y + acc[1], 0.f);
        const float h2 = fmaxf(a0.z + acc[2], 0.f);
        const float h3 = fmaxf(a0.w + acc[3], 0.f);
        const float h4 = fmaxf(a1.x + acc[4], 0.f);
        const float h5 = fmaxf(a1.y + acc[5], 0.f);
        const float h6 = fmaxf(a1.z + acc[6], 0.f);
        const float h7 = fmaxf(a1.w + acc[7], 0.f);
        uint4 o;
        o.x = bf16pair(h0, h1);
        o.y = bf16pair(h2, h3);
        o.z = bf16pair(h4, h5);
        o.w = bf16pair(h6, h7);
        *(uint4*)(h16 + (size_t)n * HID + cl * 8) = o;
    }
}

// ---------------------------------------------------------------------------
// Kernel 5: MFMA decoder (proven). h (bf16) @ W_dec(->bf16) + b_dec -> f32.
// ---------------------------------------------------------------------------
__global__ __launch_bounds__(256) void graphmae_decode(
    const unsigned short* __restrict__ h16, const float* __restrict__ W_dec,
    const float* __restrict__ b_dec, float* __restrict__ out, int N)
{
    __shared__ unsigned short As[64][72];
    __shared__ unsigned short Bs[128][72];

    const int t  = threadIdx.x;
    const int n0 = blockIdx.x * 64;

    {
        const int r = t >> 2, q = t & 3;
        const int n = n0 + r;
        unsigned short* ap = &As[r][q * 16];
        if (n < N) {
            const unsigned short* hp = h16 + (size_t)n * HID + q * 16;
            #pragma unroll
            for (int j = 0; j < 4; ++j)
                *(uint2*)(ap + j * 4) = *(const uint2*)(hp + j * 4);
        } else {
            #pragma unroll
            for (int j = 0; j < 4; ++j) *(uint2*)(ap + j * 4) = make_uint2(0u, 0u);
        }
    }
    #pragma unroll
    for (int p = 0; p < 8; ++p) {
        const int idx = t + p * 256;
        const int k   = idx >> 5;
        const int c4  = (idx & 31) * 4;
        const float4 v = *(const float4*)(W_dec + (size_t)k * IN_CH + c4);
        Bs[c4 + 0][k] = bf16of(v.x);
        Bs[c4 + 1][k] = bf16of(v.y);
        Bs[c4 + 2][k] = bf16of(v.z);
        Bs[c4 + 3][k] = bf16of(v.w);
    }
    __syncthreads();

    const int w    = t >> 6;
    const int lane = t & 63;
    const int mr   = lane & 15;
    const int kg   = lane >> 4;

    v8s afrag[2];
    #pragma unroll
    for (int ks = 0; ks < 2; ++ks)
        afrag[ks] = *(const v8s*)(&As[w * 16 + mr][ks * 32 + kg * 8]);

    const int rbase = n0 + w * 16 + kg * 4;
    #pragma unroll
    for (int ct = 0; ct < 8; ++ct) {
        v4f acc = {0.f, 0.f, 0.f, 0.f};
        #pragma unroll
        for (int ks = 0; ks < 2; ++ks) {
            const v8s b = *(const v8s*)(&Bs[ct * 16 + mr][ks * 32 + kg * 8]);
            acc = __builtin_amdgcn_mfma_f32_16x16x32_bf16(afrag[ks], b, acc, 0, 0, 0);
        }
        const int c  = ct * 16 + mr;
        const float bd = b_dec[c];
        #pragma unroll
        for (int r = 0; r < 4; ++r) {
            const int n = rbase + r;
            if (n < N) out[(size_t)n * IN_CH + c] = acc[r] + bd;
        }
    }
}

// ---------------------------------------------------------------------------
extern "C" void kernel_launch(void* const* d_in, const int* in_sizes, int n_in,
                              void* d_out, int out_size, void* d_ws, size_t ws_size,
                              hipStream_t stream)
{
    const float* x      = (const float*)d_in[0];
    const int*   ei     = (const int*)  d_in[1];   // [2][E] int32
    const float* W_rel  = (const float*)d_in[2];
    const float* b_rel  = (const float*)d_in[3];
    const float* W_root = (const float*)d_in[4];
    const float* W_dec  = (const float*)d_in[5];
    const float* b_dec  = (const float*)d_in[6];
    float* out = (float*)d_out;

    const int N = in_sizes[0] / IN_CH;
    const int E = in_sizes[1] / 2;

    const int NBUK = (N + 255) / 256;      // 196 buckets (dst>>8)
    const int NPAD = NBUK * 256;           // 50176 padded node rows
    const int CE   = (E + NSCAT - 1) / NSCAT;

    unsigned short* y16 = (unsigned short*)d_ws;                   // [N][64] bf16
    float* agg          = (float*)(y16 + (size_t)N * HID);         // [N][64] f32
    unsigned short* h16 = (unsigned short*)(agg + (size_t)N * HID);// [N][64] bf16
    int* deg            = (int*)(h16 + (size_t)N * HID);           // [NPAD]
    unsigned short* slots16 = (unsigned short*)(deg + NPAD);       // [NPAD*ELLW]
    unsigned int* sorted = (unsigned int*)(slots16 + (size_t)NPAD * ELLW); // [NBUK*BCAP]
    int* bucketcur = (int*)(sorted + (size_t)NBUK * BCAP);         // [NBUK]
    int* spillcnt  = bucketcur + NBUK;                             // [1]+pad
    int2* spill    = (int2*)(spillcnt + 3);                        // [SPILLCAP]

    // zero bucketcur + spillcnt (contiguous, capture-safe)
    hipMemsetAsync(bucketcur, 0, (size_t)(NBUK + 1) * sizeof(int), stream);

    const int nblk32 = (N + 31) / 32;
    const int nblk64 = (N + 63) / 64;

    graphmae_encode<<<nblk32, 256, 0, stream>>>(x, W_rel, b_rel, W_root,
                                                (unsigned int*)y16, agg, N);
    edge_scatter<<<NSCAT, 256, 0, stream>>>(ei, bucketcur, sorted,
                                            spillcnt, spill, E, NBUK, CE);
    bucket_fill <<<NBUK,  256, 0, stream>>>(sorted, bucketcur, deg, slots16,
                                            spillcnt, spill);

    const int gblk = (N + 3) / 4;
    graphmae_gather<<<gblk, 256, 0, stream>>>(deg, slots16, y16, agg,
                                              spillcnt, spill, h16, N);
    graphmae_decode<<<nblk64, 256, 0, stream>>>(h16, W_dec, b_dec, out, N);
}

// Round 16
// 91.639 us; speedup vs baseline: 1.5477x; 1.2320x over previous
//
#include <hip/hip_runtime.h>

#define IN_CH 128
#define HID 64
#define ELLW 32        // 32 x ushort = 64B per node row
#define SPILLCAP 4096  // overflow edges (P ~ 0 for this graph)
#define NSCAT 64       // blocks carrying scatter duty (low returned-atomic count)
#define BCAP 3584      // fixed region capacity per 256-node bucket (mean 3061, +9 sigma)

typedef short v8s __attribute__((ext_vector_type(8)));   // 8 bf16 (4 VGPRs)
typedef float v4f __attribute__((ext_vector_type(4)));   // 4 f32 acc

// branch-free f32 -> bf16 (round-to-nearest-even), pure uint math
__device__ __forceinline__ unsigned int bf16pair(float a, float b) {
    unsigned int ua = __float_as_uint(a);
    unsigned int ub = __float_as_uint(b);
    ua = (ua + 0x7fffu + ((ua >> 16) & 1u)) >> 16;          // elem0 -> low 16
    ub = (ub + 0x7fffu + ((ub >> 16) & 1u)) & 0xffff0000u;  // elem1 -> high 16
    return ua | ub;
}
__device__ __forceinline__ unsigned short bf16of(float a) {
    unsigned int ua = __float_as_uint(a);
    return (unsigned short)((ua + 0x7fffu + ((ua >> 16) & 1u)) >> 16);
}

// ---------------------------------------------------------------------------
// Kernel 1: fused encoder GEMMs + bucket scatter (co-resident waves).
// 512 threads: t<256 = proven R5 VALU encode (verbatim); t>=256 = scatter
// duty on blocks 0..NSCAT-1 only. Scatter phases mapped to the existing
// barrier structure:
//   top               : zero LDS hist/cursors
//   kh=0 compute      : LDS histogram of the block's edge chunk
//   kh=1 staging      : reserve bucket space (1 returned atomic/bucket)
//   kh=1 compute      : write packed edges at LDS cursor positions
// ---------------------------------------------------------------------------
__global__ __launch_bounds__(512) void graphmae_encode_scatter(
    const float* __restrict__ x, const float* __restrict__ W_rel,
    const float* __restrict__ b_rel, const float* __restrict__ W_root,
    const int* __restrict__ ei,
    unsigned int* __restrict__ y_relw, float* __restrict__ agg,
    int* __restrict__ bucketcur, unsigned int* __restrict__ sorted,
    int* __restrict__ spillcnt, int2* __restrict__ spill,
    int N, int E, int NBUK, int CE)
{
    __shared__ float lw[64 * 128];   // k-half of [W_rel | W_root]
    __shared__ float xs[32 * 132];   // 32 x-rows, padded
    __shared__ int   lh[256];        // scatter: per-bucket local count
    __shared__ int   lcur[256];      // scatter: reserved base -> running cursor

    const int t  = threadIdx.x;
    const int tc = t & 31;
    const int tr = (t & 255) >> 5;
    const int n0 = blockIdx.x * 32;
    const bool sduty = (blockIdx.x < NSCAT);
    const int e0 = blockIdx.x * CE;
    const int e1 = sduty ? min(E, e0 + CE) : 0;

    if (t < 256) {
        #pragma unroll
        for (int p = 0; p < 4; ++p) {
            const int row = tr + p * 8;
            const int n   = n0 + row;
            float4 v = make_float4(0.f, 0.f, 0.f, 0.f);
            if (n < N) v = *(const float4*)(x + (size_t)n * IN_CH + tc * 4);
            *(float4*)(xs + row * 132 + tc * 4) = v;
        }
    } else {
        lh[t - 256] = 0;
        lcur[t - 256] = 0;
    }

    float acc[4][4];
    #pragma unroll
    for (int i = 0; i < 4; ++i)
        #pragma unroll
        for (int j = 0; j < 4; ++j) acc[i][j] = 0.f;

    for (int kh = 0; kh < 2; ++kh) {
        __syncthreads();   // B1: prev compute done (kh=1: hist complete)
        if (t < 256) {
            #pragma unroll
            for (int p = 0; p < 8; ++p) {
                const int idx  = t + p * 256;
                const int krow = idx >> 5;
                const int col4 = (idx & 31) * 4;
                float4 v;
                if (col4 < HID)
                    v = *(const float4*)(W_rel  + (size_t)(kh * 64 + krow) * HID + col4);
                else
                    v = *(const float4*)(W_root + (size_t)(kh * 64 + krow) * HID + (col4 - HID));
                *(float4*)(lw + idx * 4) = v;
            }
        } else if (kh == 1 && sduty) {
            // ---- reserve: one returned global atomic per (block,bucket) ----
            const int b = t - 256;
            if (b < NBUK) {
                const int cnt = lh[b];
                if (cnt > 0) lcur[b] = atomicAdd(&bucketcur[b], cnt);
            }
        }
        __syncthreads();   // B2: staging done (kh=1: cursors ready)

        if (t < 256) {
            #pragma unroll 2
            for (int k = 0; k < 64; k += 4) {
                float4 w0 = *(const float4*)(lw + (k + 0) * 128 + tc * 4);
                float4 w1 = *(const float4*)(lw + (k + 1) * 128 + tc * 4);
                float4 w2 = *(const float4*)(lw + (k + 2) * 128 + tc * 4);
                float4 w3 = *(const float4*)(lw + (k + 3) * 128 + tc * 4);
                const float* w0f = (const float*)&w0;
                const float* w1f = (const float*)&w1;
                const float* w2f = (const float*)&w2;
                const float* w3f = (const float*)&w3;
                #pragma unroll
                for (int i = 0; i < 4; ++i) {
                    const float4 xv = *(const float4*)(xs + (tr * 4 + i) * 132 + kh * 64 + k);
                    const float* xf = (const float*)&xv;
                    #pragma unroll
                    for (int j = 0; j < 4; ++j) {
                        acc[i][j] += xf[0] * w0f[j];
                        acc[i][j] += xf[1] * w1f[j];
                        acc[i][j] += xf[2] * w2f[j];
                        acc[i][j] += xf[3] * w3f[j];
                    }
                }
            }
        } else if (sduty) {
            if (kh == 0) {
                // ---- hist: LDS atomics over the block's edge chunk ----
                for (int e = e0 + (t - 256); e < e1; e += 256)
                    atomicAdd(&lh[ei[E + e] >> 8], 1);
            } else {
                // ---- write: packed edges at LDS cursor positions ----
                for (int e = e0 + (t - 256); e < e1; e += 256) {
                    const int d = ei[E + e];
                    const int s = ei[e];
                    const int b = d >> 8;
                    const int pos = atomicAdd(&lcur[b], 1);
                    if (pos - (lh[b] ? 0 : 0) >= 0 && pos < BCAP + lcur[b]) {}
                    if (pos < BCAP) {
                        // pos is absolute only if base+offset < BCAP region cap:
                        // lcur holds absolute positions (base from reserve).
                        sorted[(size_t)b * BCAP + pos] =
                            ((unsigned)(d & 255) << 16) | (unsigned)s;
                    } else {
                        const int p = atomicAdd(spillcnt, 1);   // statistically never
                        if (p < SPILLCAP) spill[p] = make_int2(d, s);
                    }
                }
            }
        }
    }

    if (t < 256) {
        const int c0 = (tc & 15) * 4;
        if (tc < 16) {
            #pragma unroll
            for (int i = 0; i < 4; ++i) {
                const int n = n0 + tr * 4 + i;
                if (n < N) {
                    const unsigned int lo = bf16pair(acc[i][0], acc[i][1]);
                    const unsigned int hi = bf16pair(acc[i][2], acc[i][3]);
                    *(uint2*)(y_relw + (size_t)n * 32 + (c0 >> 1)) = make_uint2(lo, hi);
                }
            }
        } else {
            const float4 br = *(const float4*)(b_rel + c0);
            #pragma unroll
            for (int i = 0; i < 4; ++i) {
                const int n = n0 + tr * 4 + i;
                if (n < N)
                    *(float4*)(agg + (size_t)n * HID + c0) =
                        make_float4(acc[i][0] + br.x, acc[i][1] + br.y,
                                    acc[i][2] + br.z, acc[i][3] + br.w);
            }
        }
    }
}

// ---------------------------------------------------------------------------
// Kernel 2: per-bucket ELL fill, entirely in LDS; coalesced 16KB writeout.
// Writes deg for EVERY padded node (no pre-zero needed).
// ---------------------------------------------------------------------------
__global__ __launch_bounds__(256) void bucket_fill(
    const unsigned int* __restrict__ sorted, const int* __restrict__ bucketcur,
    int* __restrict__ deg, unsigned short* __restrict__ slots16,
    int* __restrict__ spillcnt, int2* __restrict__ spill)
{
    __shared__ int cnt[256];
    __shared__ unsigned short sl[256 * ELLW];   // 16KB
    const int t = threadIdx.x, b = blockIdx.x;
    cnt[t] = 0;
    __syncthreads();

    const int m = min(bucketcur[b], BCAP);
    const unsigned int* src = sorted + (size_t)b * BCAP;
    for (int i = t; i < m; i += 256) {
        const unsigned int v = src[i];
        const int dl = v >> 16;
        const int r = atomicAdd(&cnt[dl], 1);       // LDS atomic — fast
        if (r < ELLW) sl[dl * ELLW + r] = (unsigned short)(v & 0xffffu);
        else {
            const int p = atomicAdd(spillcnt, 1);   // statistically never
            if (p < SPILLCAP) spill[p] = make_int2((b << 8) + dl, (int)(v & 0xffffu));
        }
    }
    __syncthreads();

    deg[(b << 8) + t] = cnt[t];
    unsigned int* g = (unsigned int*)slots16 + (size_t)b * 4096;
    const unsigned int* l = (const unsigned int*)sl;
    for (int i = t; i < 4096; i += 256) g[i] = l[i];
}

// ---------------------------------------------------------------------------
// Kernel 3: gather (proven R10-R15 structure). One wave64 per node,
// 8 edge-slots x 8 col-lanes. h = relu(agg + sum) stored bf16.
// ---------------------------------------------------------------------------
__global__ __launch_bounds__(256) void graphmae_gather(
    const int* __restrict__ deg, const unsigned short* __restrict__ slots16,
    const unsigned short* __restrict__ y16, const float* __restrict__ agg,
    const int* __restrict__ spillcnt, const int2* __restrict__ spill,
    unsigned short* __restrict__ h16, int N)
{
    const int n = blockIdx.x * 4 + (threadIdx.x >> 6);
    if (n >= N) return;
    const int lane = threadIdx.x & 63;
    const int es   = lane >> 3;
    const int cl   = lane & 7;

    const int cnt = min(deg[n], ELLW);
    const unsigned short* sp = slots16 + (size_t)n * ELLW;

    float4 a0 = make_float4(0.f, 0.f, 0.f, 0.f);
    float4 a1 = make_float4(0.f, 0.f, 0.f, 0.f);
    if (es == 0) {
        a0 = *(const float4*)(agg + (size_t)n * HID + cl * 8);
        a1 = *(const float4*)(agg + (size_t)n * HID + cl * 8 + 4);
    }

    float acc[8];
    #pragma unroll
    for (int j = 0; j < 8; ++j) acc[j] = 0.f;

    for (int e = es; e < cnt; e += 8) {
        const int s = sp[e];
        const uint4 v = *(const uint4*)(y16 + (size_t)s * HID + cl * 8);
        acc[0] += __uint_as_float(v.x << 16);
        acc[1] += __uint_as_float(v.x & 0xffff0000u);
        acc[2] += __uint_as_float(v.y << 16);
        acc[3] += __uint_as_float(v.y & 0xffff0000u);
        acc[4] += __uint_as_float(v.z << 16);
        acc[5] += __uint_as_float(v.z & 0xffff0000u);
        acc[6] += __uint_as_float(v.w << 16);
        acc[7] += __uint_as_float(v.w & 0xffff0000u);
    }

    const int spN = min(*spillcnt, SPILLCAP);
    for (int i = es; i < spN; i += 8) {
        const int2 e2 = spill[i];
        if (e2.x == n) {
            const uint4 v = *(const uint4*)(y16 + (size_t)e2.y * HID + cl * 8);
            acc[0] += __uint_as_float(v.x << 16);
            acc[1] += __uint_as_float(v.x & 0xffff0000u);
            acc[2] += __uint_as_float(v.y << 16);
            acc[3] += __uint_as_float(v.y & 0xffff0000u);
            acc[4] += __uint_as_float(v.z << 16);
            acc[5] += __uint_as_float(v.z & 0xffff0000u);
            acc[6] += __uint_as_float(v.w << 16);
            acc[7] += __uint_as_float(v.w & 0xffff0000u);
        }
    }

    #pragma unroll
    for (int m = 8; m <= 32; m <<= 1) {
        #pragma unroll
        for (int j = 0; j < 8; ++j) acc[j] += __shfl_xor(acc[j], m);
    }

    if (es == 0) {
        const float h0 = fmaxf(a0.x + acc[0], 0.f);
        const float h1 = fmaxf(a0.y + acc[1], 0.f);
        const float h2 = fmaxf(a0.z + acc[2], 0.f);
        const float h3 = fmaxf(a0.w + acc[3], 0.f);
        const float h4 = fmaxf(a1.x + acc[4], 0.f);
        const float h5 = fmaxf(a1.y + acc[5], 0.f);
        const float h6 = fmaxf(a1.z + acc[6], 0.f);
        const float h7 = fmaxf(a1.w + acc[7], 0.f);
        uint4 o;
        o.x = bf16pair(h0, h1);
        o.y = bf16pair(h2, h3);
        o.z = bf16pair(h4, h5);
        o.w = bf16pair(h6, h7);
        *(uint4*)(h16 + (size_t)n * HID + cl * 8) = o;
    }
}

// ---------------------------------------------------------------------------
// Kernel 4: MFMA decoder (proven). h (bf16) @ W_dec(->bf16) + b_dec -> f32.
// ---------------------------------------------------------------------------
__global__ __launch_bounds__(256) void graphmae_decode(
    const unsigned short* __restrict__ h16, const float* __restrict__ W_dec,
    const float* __restrict__ b_dec, float* __restrict__ out, int N)
{
    __shared__ unsigned short As[64][72];
    __shared__ unsigned short Bs[128][72];

    const int t  = threadIdx.x;
    const int n0 = blockIdx.x * 64;

    {
        const int r = t >> 2, q = t & 3;
        const int n = n0 + r;
        unsigned short* ap = &As[r][q * 16];
        if (n < N) {
            const unsigned short* hp = h16 + (size_t)n * HID + q * 16;
            #pragma unroll
            for (int j = 0; j < 4; ++j)
                *(uint2*)(ap + j * 4) = *(const uint2*)(hp + j * 4);
        } else {
            #pragma unroll
            for (int j = 0; j < 4; ++j) *(uint2*)(ap + j * 4) = make_uint2(0u, 0u);
        }
    }
    #pragma unroll
    for (int p = 0; p < 8; ++p) {
        const int idx = t + p * 256;
        const int k   = idx >> 5;
        const int c4  = (idx & 31) * 4;
        const float4 v = *(const float4*)(W_dec + (size_t)k * IN_CH + c4);
        Bs[c4 + 0][k] = bf16of(v.x);
        Bs[c4 + 1][k] = bf16of(v.y);
        Bs[c4 + 2][k] = bf16of(v.z);
        Bs[c4 + 3][k] = bf16of(v.w);
    }
    __syncthreads();

    const int w    = t >> 6;
    const int lane = t & 63;
    const int mr   = lane & 15;
    const int kg   = lane >> 4;

    v8s afrag[2];
    #pragma unroll
    for (int ks = 0; ks < 2; ++ks)
        afrag[ks] = *(const v8s*)(&As[w * 16 + mr][ks * 32 + kg * 8]);

    const int rbase = n0 + w * 16 + kg * 4;
    #pragma unroll
    for (int ct = 0; ct < 8; ++ct) {
        v4f acc = {0.f, 0.f, 0.f, 0.f};
        #pragma unroll
        for (int ks = 0; ks < 2; ++ks) {
            const v8s b = *(const v8s*)(&Bs[ct * 16 + mr][ks * 32 + kg * 8]);
            acc = __builtin_amdgcn_mfma_f32_16x16x32_bf16(afrag[ks], b, acc, 0, 0, 0);
        }
        const int c  = ct * 16 + mr;
        const float bd = b_dec[c];
        #pragma unroll
        for (int r = 0; r < 4; ++r) {
            const int n = rbase + r;
            if (n < N) out[(size_t)n * IN_CH + c] = acc[r] + bd;
        }
    }
}

// ---------------------------------------------------------------------------
extern "C" void kernel_launch(void* const* d_in, const int* in_sizes, int n_in,
                              void* d_out, int out_size, void* d_ws, size_t ws_size,
                              hipStream_t stream)
{
    const float* x      = (const float*)d_in[0];
    const int*   ei     = (const int*)  d_in[1];   // [2][E] int32
    const float* W_rel  = (const float*)d_in[2];
    const float* b_rel  = (const float*)d_in[3];
    const float* W_root = (const float*)d_in[4];
    const float* W_dec  = (const float*)d_in[5];
    const float* b_dec  = (const float*)d_in[6];
    float* out = (float*)d_out;

    const int N = in_sizes[0] / IN_CH;
    const int E = in_sizes[1] / 2;

    const int NBUK = (N + 255) / 256;      // 196 buckets (dst>>8)
    const int NPAD = NBUK * 256;           // 50176 padded node rows
    const int CE   = (E + NSCAT - 1) / NSCAT;

    unsigned short* y16 = (unsigned short*)d_ws;                   // [N][64] bf16
    float* agg          = (float*)(y16 + (size_t)N * HID);         // [N][64] f32
    unsigned short* h16 = (unsigned short*)(agg + (size_t)N * HID);// [N][64] bf16
    int* deg            = (int*)(h16 + (size_t)N * HID);           // [NPAD]
    unsigned short* slots16 = (unsigned short*)(deg + NPAD);       // [NPAD*ELLW]
    unsigned int* sorted = (unsigned int*)(slots16 + (size_t)NPAD * ELLW); // [NBUK*BCAP]
    int* bucketcur = (int*)(sorted + (size_t)NBUK * BCAP);         // [NBUK]
    int* spillcnt  = bucketcur + NBUK;                             // [1]+pad
    int2* spill    = (int2*)(spillcnt + 3);                        // [SPILLCAP]

    // zero bucketcur + spillcnt (contiguous, capture-safe)
    hipMemsetAsync(bucketcur, 0, (size_t)(NBUK + 1) * sizeof(int), stream);

    const int nblk32 = (N + 31) / 32;
    const int nblk64 = (N + 63) / 64;

    graphmae_encode_scatter<<<nblk32, 512, 0, stream>>>(
        x, W_rel, b_rel, W_root, ei, (unsigned int*)y16, agg,
        bucketcur, sorted, spillcnt, spill, N, E, NBUK, CE);

    bucket_fill<<<NBUK, 256, 0, stream>>>(sorted, bucketcur, deg, slots16,
                                          spillcnt, spill);

    const int gblk = (N + 3) / 4;
    graphmae_gather<<<gblk, 256, 0, stream>>>(deg, slots16, y16, agg,
                                              spillcnt, spill, h16, N);
    graphmae_decode<<<nblk64, 256, 0, stream>>>(h16, W_dec, b_dec, out, N);
}

// Round 17
// 89.136 us; speedup vs baseline: 1.5912x; 1.0281x over previous
//
#include <hip/hip_runtime.h>

#define IN_CH 128
#define HID 64
#define ELLW 32        // 32 x ushort = 64B per node row
#define SPILLCAP 4096  // overflow edges (P ~ 0 for this graph)
#define NSCAT 64       // blocks carrying scatter duty (low returned-atomic count)
#define BCAP 3584      // fixed region capacity per 256-node bucket (mean 3061, +9 sigma)

typedef short v8s __attribute__((ext_vector_type(8)));   // 8 bf16 (4 VGPRs)
typedef float v4f __attribute__((ext_vector_type(4)));   // 4 f32 acc

// branch-free f32 -> bf16 (round-to-nearest-even), pure uint math
__device__ __forceinline__ unsigned int bf16pair(float a, float b) {
    unsigned int ua = __float_as_uint(a);
    unsigned int ub = __float_as_uint(b);
    ua = (ua + 0x7fffu + ((ua >> 16) & 1u)) >> 16;          // elem0 -> low 16
    ub = (ub + 0x7fffu + ((ub >> 16) & 1u)) & 0xffff0000u;  // elem1 -> high 16
    return ua | ub;
}
__device__ __forceinline__ unsigned short bf16of(float a) {
    unsigned int ua = __float_as_uint(a);
    return (unsigned short)((ua + 0x7fffu + ((ua >> 16) & 1u)) >> 16);
}

// ---------------------------------------------------------------------------
// Kernel 1: fused encoder GEMMs + bucket scatter (R16 proven structure)
// + software-pipelined inner loop: next k-step's LDS reads (nw*, nx*) are
// issued BEFORE the FMAs of the current step, hiding the ~120cy ds_read
// latency under the 128cy FMA burst (R16 counters: VALUBusy 40% = stall).
// ---------------------------------------------------------------------------
__global__ __launch_bounds__(512) void graphmae_encode_scatter(
    const float* __restrict__ x, const float* __restrict__ W_rel,
    const float* __restrict__ b_rel, const float* __restrict__ W_root,
    const int* __restrict__ ei,
    unsigned int* __restrict__ y_relw, float* __restrict__ agg,
    int* __restrict__ bucketcur, unsigned int* __restrict__ sorted,
    int* __restrict__ spillcnt, int2* __restrict__ spill,
    int N, int E, int NBUK, int CE)
{
    __shared__ float lw[64 * 128];   // k-half of [W_rel | W_root]
    __shared__ float xs[32 * 132];   // 32 x-rows, padded
    __shared__ int   lh[256];        // scatter: per-bucket local count
    __shared__ int   lcur[256];      // scatter: reserved base -> running cursor

    const int t  = threadIdx.x;
    const int tc = t & 31;
    const int tr = (t & 255) >> 5;
    const int n0 = blockIdx.x * 32;
    const bool sduty = (blockIdx.x < NSCAT);
    const int e0 = blockIdx.x * CE;
    const int e1 = sduty ? min(E, e0 + CE) : 0;

    if (t < 256) {
        #pragma unroll
        for (int p = 0; p < 4; ++p) {
            const int row = tr + p * 8;
            const int n   = n0 + row;
            float4 v = make_float4(0.f, 0.f, 0.f, 0.f);
            if (n < N) v = *(const float4*)(x + (size_t)n * IN_CH + tc * 4);
            *(float4*)(xs + row * 132 + tc * 4) = v;
        }
    } else {
        lh[t - 256] = 0;
        lcur[t - 256] = 0;
    }

    float acc[4][4];
    #pragma unroll
    for (int i = 0; i < 4; ++i)
        #pragma unroll
        for (int j = 0; j < 4; ++j) acc[i][j] = 0.f;

    for (int kh = 0; kh < 2; ++kh) {
        __syncthreads();   // B1: prev compute done (kh=1: hist complete)
        if (t < 256) {
            #pragma unroll
            for (int p = 0; p < 8; ++p) {
                const int idx  = t + p * 256;
                const int krow = idx >> 5;
                const int col4 = (idx & 31) * 4;
                float4 v;
                if (col4 < HID)
                    v = *(const float4*)(W_rel  + (size_t)(kh * 64 + krow) * HID + col4);
                else
                    v = *(const float4*)(W_root + (size_t)(kh * 64 + krow) * HID + (col4 - HID));
                *(float4*)(lw + idx * 4) = v;
            }
        } else if (kh == 1 && sduty) {
            // ---- reserve: one returned global atomic per (block,bucket) ----
            const int b = t - 256;
            if (b < NBUK) {
                const int cnt = lh[b];
                if (cnt > 0) lcur[b] = atomicAdd(&bucketcur[b], cnt);
            }
        }
        __syncthreads();   // B2: staging done (kh=1: cursors ready)

        if (t < 256) {
            const float* wp = lw + tc * 4;
            const float* xp = xs + (tr * 4) * 132 + kh * 64;
            // preload k=0
            float4 w0 = *(const float4*)(wp + 0 * 128);
            float4 w1 = *(const float4*)(wp + 1 * 128);
            float4 w2 = *(const float4*)(wp + 2 * 128);
            float4 w3 = *(const float4*)(wp + 3 * 128);
            float4 x0 = *(const float4*)(xp + 0 * 132);
            float4 x1 = *(const float4*)(xp + 1 * 132);
            float4 x2 = *(const float4*)(xp + 2 * 132);
            float4 x3 = *(const float4*)(xp + 3 * 132);
            for (int k = 0; k < 64; k += 4) {
                // issue next step's reads BEFORE this step's FMAs
                const int kn = (k + 4 < 64) ? k + 4 : 0;
                float4 nw0 = *(const float4*)(wp + (kn + 0) * 128);
                float4 nw1 = *(const float4*)(wp + (kn + 1) * 128);
                float4 nw2 = *(const float4*)(wp + (kn + 2) * 128);
                float4 nw3 = *(const float4*)(wp + (kn + 3) * 128);
                float4 nx0 = *(const float4*)(xp + 0 * 132 + kn);
                float4 nx1 = *(const float4*)(xp + 1 * 132 + kn);
                float4 nx2 = *(const float4*)(xp + 2 * 132 + kn);
                float4 nx3 = *(const float4*)(xp + 3 * 132 + kn);

                const float* w0f = (const float*)&w0;
                const float* w1f = (const float*)&w1;
                const float* w2f = (const float*)&w2;
                const float* w3f = (const float*)&w3;
                const float4 xv[4] = {x0, x1, x2, x3};
                #pragma unroll
                for (int i = 0; i < 4; ++i) {
                    const float* xf = (const float*)&xv[i];
                    #pragma unroll
                    for (int j = 0; j < 4; ++j) {
                        acc[i][j] += xf[0] * w0f[j];
                        acc[i][j] += xf[1] * w1f[j];
                        acc[i][j] += xf[2] * w2f[j];
                        acc[i][j] += xf[3] * w3f[j];
                    }
                }
                w0 = nw0; w1 = nw1; w2 = nw2; w3 = nw3;
                x0 = nx0; x1 = nx1; x2 = nx2; x3 = nx3;
            }
        } else if (sduty) {
            if (kh == 0) {
                // ---- hist: LDS atomics over the block's edge chunk ----
                for (int e = e0 + (t - 256); e < e1; e += 256)
                    atomicAdd(&lh[ei[E + e] >> 8], 1);
            } else {
                // ---- write: packed edges at LDS cursor positions ----
                for (int e = e0 + (t - 256); e < e1; e += 256) {
                    const int d = ei[E + e];
                    const int s = ei[e];
                    const int b = d >> 8;
                    const int pos = atomicAdd(&lcur[b], 1);
                    if (pos < BCAP) {
                        sorted[(size_t)b * BCAP + pos] =
                            ((unsigned)(d & 255) << 16) | (unsigned)s;
                    } else {
                        const int p = atomicAdd(spillcnt, 1);   // statistically never
                        if (p < SPILLCAP) spill[p] = make_int2(d, s);
                    }
                }
            }
        }
    }

    if (t < 256) {
        const int c0 = (tc & 15) * 4;
        if (tc < 16) {
            #pragma unroll
            for (int i = 0; i < 4; ++i) {
                const int n = n0 + tr * 4 + i;
                if (n < N) {
                    const unsigned int lo = bf16pair(acc[i][0], acc[i][1]);
                    const unsigned int hi = bf16pair(acc[i][2], acc[i][3]);
                    *(uint2*)(y_relw + (size_t)n * 32 + (c0 >> 1)) = make_uint2(lo, hi);
                }
            }
        } else {
            const float4 br = *(const float4*)(b_rel + c0);
            #pragma unroll
            for (int i = 0; i < 4; ++i) {
                const int n = n0 + tr * 4 + i;
                if (n < N)
                    *(float4*)(agg + (size_t)n * HID + c0) =
                        make_float4(acc[i][0] + br.x, acc[i][1] + br.y,
                                    acc[i][2] + br.z, acc[i][3] + br.w);
            }
        }
    }
}

// ---------------------------------------------------------------------------
// Kernel 2: per-bucket ELL fill, entirely in LDS; coalesced 16KB writeout.
// Writes deg for EVERY padded node (no pre-zero needed).
// ---------------------------------------------------------------------------
__global__ __launch_bounds__(256) void bucket_fill(
    const unsigned int* __restrict__ sorted, const int* __restrict__ bucketcur,
    int* __restrict__ deg, unsigned short* __restrict__ slots16,
    int* __restrict__ spillcnt, int2* __restrict__ spill)
{
    __shared__ int cnt[256];
    __shared__ unsigned short sl[256 * ELLW];   // 16KB
    const int t = threadIdx.x, b = blockIdx.x;
    cnt[t] = 0;
    __syncthreads();

    const int m = min(bucketcur[b], BCAP);
    const unsigned int* src = sorted + (size_t)b * BCAP;
    for (int i = t; i < m; i += 256) {
        const unsigned int v = src[i];
        const int dl = v >> 16;
        const int r = atomicAdd(&cnt[dl], 1);       // LDS atomic — fast
        if (r < ELLW) sl[dl * ELLW + r] = (unsigned short)(v & 0xffffu);
        else {
            const int p = atomicAdd(spillcnt, 1);   // statistically never
            if (p < SPILLCAP) spill[p] = make_int2((b << 8) + dl, (int)(v & 0xffffu));
        }
    }
    __syncthreads();

    deg[(b << 8) + t] = cnt[t];
    unsigned int* g = (unsigned int*)slots16 + (size_t)b * 4096;
    const unsigned int* l = (const unsigned int*)sl;
    for (int i = t; i < 4096; i += 256) g[i] = l[i];
}

// ---------------------------------------------------------------------------
// Kernel 3: gather (proven R10-R16 structure). One wave64 per node,
// 8 edge-slots x 8 col-lanes. h = relu(agg + sum) stored bf16.
// ---------------------------------------------------------------------------
__global__ __launch_bounds__(256) void graphmae_gather(
    const int* __restrict__ deg, const unsigned short* __restrict__ slots16,
    const unsigned short* __restrict__ y16, const float* __restrict__ agg,
    const int* __restrict__ spillcnt, const int2* __restrict__ spill,
    unsigned short* __restrict__ h16, int N)
{
    const int n = blockIdx.x * 4 + (threadIdx.x >> 6);
    if (n >= N) return;
    const int lane = threadIdx.x & 63;
    const int es   = lane >> 3;
    const int cl   = lane & 7;

    const int cnt = min(deg[n], ELLW);
    const unsigned short* sp = slots16 + (size_t)n * ELLW;

    float4 a0 = make_float4(0.f, 0.f, 0.f, 0.f);
    float4 a1 = make_float4(0.f, 0.f, 0.f, 0.f);
    if (es == 0) {
        a0 = *(const float4*)(agg + (size_t)n * HID + cl * 8);
        a1 = *(const float4*)(agg + (size_t)n * HID + cl * 8 + 4);
    }

    float acc[8];
    #pragma unroll
    for (int j = 0; j < 8; ++j) acc[j] = 0.f;

    for (int e = es; e < cnt; e += 8) {
        const int s = sp[e];
        const uint4 v = *(const uint4*)(y16 + (size_t)s * HID + cl * 8);
        acc[0] += __uint_as_float(v.x << 16);
        acc[1] += __uint_as_float(v.x & 0xffff0000u);
        acc[2] += __uint_as_float(v.y << 16);
        acc[3] += __uint_as_float(v.y & 0xffff0000u);
        acc[4] += __uint_as_float(v.z << 16);
        acc[5] += __uint_as_float(v.z & 0xffff0000u);
        acc[6] += __uint_as_float(v.w << 16);
        acc[7] += __uint_as_float(v.w & 0xffff0000u);
    }

    const int spN = min(*spillcnt, SPILLCAP);
    for (int i = es; i < spN; i += 8) {
        const int2 e2 = spill[i];
        if (e2.x == n) {
            const uint4 v = *(const uint4*)(y16 + (size_t)e2.y * HID + cl * 8);
            acc[0] += __uint_as_float(v.x << 16);
            acc[1] += __uint_as_float(v.x & 0xffff0000u);
            acc[2] += __uint_as_float(v.y << 16);
            acc[3] += __uint_as_float(v.y & 0xffff0000u);
            acc[4] += __uint_as_float(v.z << 16);
            acc[5] += __uint_as_float(v.z & 0xffff0000u);
            acc[6] += __uint_as_float(v.w << 16);
            acc[7] += __uint_as_float(v.w & 0xffff0000u);
        }
    }

    #pragma unroll
    for (int m = 8; m <= 32; m <<= 1) {
        #pragma unroll
        for (int j = 0; j < 8; ++j) acc[j] += __shfl_xor(acc[j], m);
    }

    if (es == 0) {
        const float h0 = fmaxf(a0.x + acc[0], 0.f);
        const float h1 = fmaxf(a0.y + acc[1], 0.f);
        const float h2 = fmaxf(a0.z + acc[2], 0.f);
        const float h3 = fmaxf(a0.w + acc[3], 0.f);
        const float h4 = fmaxf(a1.x + acc[4], 0.f);
        const float h5 = fmaxf(a1.y + acc[5], 0.f);
        const float h6 = fmaxf(a1.z + acc[6], 0.f);
        const float h7 = fmaxf(a1.w + acc[7], 0.f);
        uint4 o;
        o.x = bf16pair(h0, h1);
        o.y = bf16pair(h2, h3);
        o.z = bf16pair(h4, h5);
        o.w = bf16pair(h6, h7);
        *(uint4*)(h16 + (size_t)n * HID + cl * 8) = o;
    }
}

// ---------------------------------------------------------------------------
// Kernel 4: MFMA decoder (proven). h (bf16) @ W_dec(->bf16) + b_dec -> f32.
// ---------------------------------------------------------------------------
__global__ __launch_bounds__(256) void graphmae_decode(
    const unsigned short* __restrict__ h16, const float* __restrict__ W_dec,
    const float* __restrict__ b_dec, float* __restrict__ out, int N)
{
    __shared__ unsigned short As[64][72];
    __shared__ unsigned short Bs[128][72];

    const int t  = threadIdx.x;
    const int n0 = blockIdx.x * 64;

    {
        const int r = t >> 2, q = t & 3;
        const int n = n0 + r;
        unsigned short* ap = &As[r][q * 16];
        if (n < N) {
            const unsigned short* hp = h16 + (size_t)n * HID + q * 16;
            #pragma unroll
            for (int j = 0; j < 4; ++j)
                *(uint2*)(ap + j * 4) = *(const uint2*)(hp + j * 4);
        } else {
            #pragma unroll
            for (int j = 0; j < 4; ++j) *(uint2*)(ap + j * 4) = make_uint2(0u, 0u);
        }
    }
    #pragma unroll
    for (int p = 0; p < 8; ++p) {
        const int idx = t + p * 256;
        const int k   = idx >> 5;
        const int c4  = (idx & 31) * 4;
        const float4 v = *(const float4*)(W_dec + (size_t)k * IN_CH + c4);
        Bs[c4 + 0][k] = bf16of(v.x);
        Bs[c4 + 1][k] = bf16of(v.y);
        Bs[c4 + 2][k] = bf16of(v.z);
        Bs[c4 + 3][k] = bf16of(v.w);
    }
    __syncthreads();

    const int w    = t >> 6;
    const int lane = t & 63;
    const int mr   = lane & 15;
    const int kg   = lane >> 4;

    v8s afrag[2];
    #pragma unroll
    for (int ks = 0; ks < 2; ++ks)
        afrag[ks] = *(const v8s*)(&As[w * 16 + mr][ks * 32 + kg * 8]);

    const int rbase = n0 + w * 16 + kg * 4;
    #pragma unroll
    for (int ct = 0; ct < 8; ++ct) {
        v4f acc = {0.f, 0.f, 0.f, 0.f};
        #pragma unroll
        for (int ks = 0; ks < 2; ++ks) {
            const v8s b = *(const v8s*)(&Bs[ct * 16 + mr][ks * 32 + kg * 8]);
            acc = __builtin_amdgcn_mfma_f32_16x16x32_bf16(afrag[ks], b, acc, 0, 0, 0);
        }
        const int c  = ct * 16 + mr;
        const float bd = b_dec[c];
        #pragma unroll
        for (int r = 0; r < 4; ++r) {
            const int n = rbase + r;
            if (n < N) out[(size_t)n * IN_CH + c] = acc[r] + bd;
        }
    }
}

// ---------------------------------------------------------------------------
extern "C" void kernel_launch(void* const* d_in, const int* in_sizes, int n_in,
                              void* d_out, int out_size, void* d_ws, size_t ws_size,
                              hipStream_t stream)
{
    const float* x      = (const float*)d_in[0];
    const int*   ei     = (const int*)  d_in[1];   // [2][E] int32
    const float* W_rel  = (const float*)d_in[2];
    const float* b_rel  = (const float*)d_in[3];
    const float* W_root = (const float*)d_in[4];
    const float* W_dec  = (const float*)d_in[5];
    const float* b_dec  = (const float*)d_in[6];
    float* out = (float*)d_out;

    const int N = in_sizes[0] / IN_CH;
    const int E = in_sizes[1] / 2;

    const int NBUK = (N + 255) / 256;      // 196 buckets (dst>>8)
    const int NPAD = NBUK * 256;           // 50176 padded node rows
    const int CE   = (E + NSCAT - 1) / NSCAT;

    unsigned short* y16 = (unsigned short*)d_ws;                   // [N][64] bf16
    float* agg          = (float*)(y16 + (size_t)N * HID);         // [N][64] f32
    unsigned short* h16 = (unsigned short*)(agg + (size_t)N * HID);// [N][64] bf16
    int* deg            = (int*)(h16 + (size_t)N * HID);           // [NPAD]
    unsigned short* slots16 = (unsigned short*)(deg + NPAD);       // [NPAD*ELLW]
    unsigned int* sorted = (unsigned int*)(slots16 + (size_t)NPAD * ELLW); // [NBUK*BCAP]
    int* bucketcur = (int*)(sorted + (size_t)NBUK * BCAP);         // [NBUK]
    int* spillcnt  = bucketcur + NBUK;                             // [1]+pad
    int2* spill    = (int2*)(spillcnt + 3);                        // [SPILLCAP]

    // zero bucketcur + spillcnt (contiguous, capture-safe)
    hipMemsetAsync(bucketcur, 0, (size_t)(NBUK + 1) * sizeof(int), stream);

    const int nblk32 = (N + 31) / 32;
    const int nblk64 = (N + 63) / 64;

    graphmae_encode_scatter<<<nblk32, 512, 0, stream>>>(
        x, W_rel, b_rel, W_root, ei, (unsigned int*)y16, agg,
        bucketcur, sorted, spillcnt, spill, N, E, NBUK, CE);

    bucket_fill<<<NBUK, 256, 0, stream>>>(sorted, bucketcur, deg, slots16,
                                          spillcnt, spill);

    const int gblk = (N + 3) / 4;
    graphmae_gather<<<gblk, 256, 0, stream>>>(deg, slots16, y16, agg,
                                              spillcnt, spill, h16, N);
    graphmae_decode<<<nblk64, 256, 0, stream>>>(h16, W_dec, b_dec, out, N);
}